// Round 14
// baseline (181.050 us; speedup 1.0000x reference)
//
#include <hip/hip_runtime.h>

typedef _Float16 f16x8 __attribute__((ext_vector_type(8)));
typedef _Float16 f16x4 __attribute__((ext_vector_type(4)));
typedef float f32x4 __attribute__((ext_vector_type(4)));

static constexpr int S = 4;
static constexpr int NATOMS = 32768;
static constexpr int FIN = 512;
static constexpr int H = 256;
static constexpr int BM = 128;   // atoms per block
static constexpr int XSTR = 36;  // 32 fp16 + 4 pad (72B rows: 2-way banks, free)
static constexpr int HSTR = 264; // h plane: 256 cols + 8 pad fp16 (528B rows, 2-way)
static constexpr int NSTRUCT = 512;
static constexpr int RBLK = 128;
static constexpr int APB = (S * NATOMS) / RBLK;  // 1024

// ---- weight packing: fp32 [S][K][H] -> per-(s,wn) consumption-order fp16 stream
// Stream layout: [s*4 + (ntile>>2)][p][lane][8]; p = kt*4 + (ntile&3).
__global__ void pack_w(const float* __restrict__ W, _Float16* __restrict__ dst, int KT) {
    int idx = blockIdx.x * 256 + threadIdx.x;
    int j = idx & 7;
    int lane = (idx >> 3) & 63;
    int rest = idx >> 9;
    int kt = rest % KT;
    int t2 = rest / KT;            // s*16 + ntile
    int K = KT * 32;
    int k = kt * 32 + (lane >> 4) * 8 + j;
    int ntile = t2 & 15;
    int s = t2 >> 4;
    int n = ntile * 16 + (lane & 15);
    int p = kt * 4 + (ntile & 3);
    size_t o = ((((size_t)(s * 4 + (ntile >> 2))) * (KT * 4) + p) * 64 + lane) * 8 + j;
    dst[o] = (_Float16)W[((size_t)s * K + k) * H + n];
}

__global__ __launch_bounds__(512, 3) void fused_mlp(
    const float* __restrict__ X,
    const _Float16* __restrict__ W1p, const _Float16* __restrict__ W2p,
    const _Float16* __restrict__ W3p,
    const float* __restrict__ b1, const float* __restrict__ b2,
    const float* __restrict__ b3,
    const float* __restrict__ W4, const float* __restrict__ b4,
    float* __restrict__ Eout)
{
    // union: X fp16 triple buffer [3][128][36] (27648B) aliased by h fp16 plane
    // [128][264] (67584B). h written only after all layer-1 LDS reads are done.
    __shared__ _Float16 smem[BM * HSTR];
    __shared__ float e_lds[4][BM];

    const int s = blockIdx.y;
    const int tile = blockIdx.x;
    const int tid = threadIdx.x;
    const int rw = __builtin_amdgcn_readfirstlane(tid >> 6);  // wave idx -> SGPR
    const int wm = rw >> 2;        // 0..1: M-half (64 atoms)
    const int wn = rw & 3;         // 0..3: 64-col slice of H
    const int lane = tid & 63;
    const int g = lane >> 4;
    const int mh = lane & 15;
    const int srow = tid >> 2;     // staging row (128 rows, 4 threads/row)
    const int cq = tid & 3;        // staging col group (8 floats)

    const float* Xb = X + (size_t)(s * NATOMS + tile * BM) * FIN;
    _Float16* hb = smem;

    // per-(s,wn) contiguous weight streams, shared by the wm-pair (L1 broadcast)
    const _Float16* Wb1 = W1p + ((size_t)(s * 4 + wn)) * (64 * 512) + lane * 8;
    const _Float16* Wb2 = W2p + ((size_t)(s * 4 + wn)) * (32 * 512) + lane * 8;
    const _Float16* Wb3 = W3p + ((size_t)(s * 4 + wn)) * (32 * 512) + lane * 8;

    f32x4 acc[4][4];
#pragma unroll
    for (int i = 0; i < 4; ++i)
#pragma unroll
        for (int j = 0; j < 4; ++j)
            acc[i][j] = f32x4{0.f, 0.f, 0.f, 0.f};

    // ---- explicit weight-register double buffer: chunk c+1's B-frags are IN
    // FLIGHT while chunk c's MFMAs run (loads issued before the barrier asm;
    // s_barrier does not drain vmcnt). This removes the L2-latency window that
    // sat serially in front of every MFMA cluster. ----
    f16x8 wr[2][4];
    auto loadW = [&](const _Float16* Wb, int buf, int p) {
#pragma unroll
        for (int nt = 0; nt < 4; ++nt)
            wr[buf][nt] = *(const f16x8*)(Wb + (p * 4 + nt) * 512);
    };

    // ---- layer-1 staging: global->reg (f32) -> cvt once -> LDS (f16) ----
    f32x4 ld[3][2];
    auto loadc = [&](int slot, int c) {
        const float* p = Xb + (size_t)srow * FIN + c * 32 + cq * 8;
        ld[slot][0] = *(const f32x4*)(p);
        ld[slot][1] = *(const f32x4*)(p + 4);
    };
    auto storec = [&](int slot, int c) {
        _Float16* xb = smem + (c % 3) * (BM * XSTR);
#pragma unroll
        for (int i = 0; i < 2; ++i) {
            f16x4 v;
#pragma unroll
            for (int j = 0; j < 4; ++j) v[j] = (_Float16)ld[slot][i][j];
            *(f16x4*)(xb + srow * XSTR + cq * 8 + i * 4) = v;
        }
    };
    auto l1mfma = [&](int c, int buf) {   // one MFMA-K (32) per chunk
        const _Float16* xb = smem + (c % 3) * (BM * XSTR);
        f16x8 a[4];
#pragma unroll
        for (int mt = 0; mt < 4; ++mt)
            a[mt] = *(const f16x8*)(xb + (wm * 64 + mt * 16 + mh) * XSTR + g * 8);
        __builtin_amdgcn_s_setprio(1);
#pragma unroll
        for (int nt = 0; nt < 4; ++nt)
#pragma unroll
            for (int mt = 0; mt < 4; ++mt)
                acc[mt][nt] = __builtin_amdgcn_mfma_f32_16x16x32_f16(a[mt], wr[buf][nt], acc[mt][nt], 0, 0, 0);
        __builtin_amdgcn_s_setprio(0);
    };

    // ---------------- layer 1: [128x512] @ [512x256], 16 chunks ----------------
    loadW(Wb1, 0, 0);
    loadc(0, 0);
    loadc(1, 1);
    loadc(2, 2);
    storec(0, 0);
    asm volatile("s_waitcnt lgkmcnt(0)" ::: "memory");
    __builtin_amdgcn_s_barrier();
#pragma unroll
    for (int c = 0; c < 16; ++c) {
        if (c < 15) loadW(Wb1, (c + 1) & 1, c + 1);  // next chunk's B-frags in flight
        if (c < 15) storec((c + 1) % 3, c + 1);      // slot holds chunk c+1
        if (c < 13) loadc(c % 3, c + 3);
        l1mfma(c, c & 1);
        asm volatile("s_waitcnt lgkmcnt(0)" ::: "memory");
        __builtin_amdgcn_s_barrier();
    }
    __syncthreads();  // full drain before h overwrites the X union

    // bias + silu -> h1 (fp16 plane)
    {
        float bv[4];
#pragma unroll
        for (int nt = 0; nt < 4; ++nt) bv[nt] = b1[s * H + wn * 64 + nt * 16 + mh];
#pragma unroll
        for (int mt = 0; mt < 4; ++mt)
#pragma unroll
            for (int nt = 0; nt < 4; ++nt)
#pragma unroll
                for (int r = 0; r < 4; ++r) {
                    float v = acc[mt][nt][r] + bv[nt];
                    v = __fdividef(v, 1.f + __expf(-v));
                    hb[(wm * 64 + mt * 16 + g * 4 + r) * HSTR + wn * 64 + nt * 16 + mh] = (_Float16)v;
                    acc[mt][nt][r] = 0.f;
                }
    }
    __syncthreads();

    // ---------------- layers 2 and 3: [128x256] @ [256x256] ----------------
    for (int l = 0; l < 2; ++l) {
        const _Float16* Wb = l ? Wb3 : Wb2;
        loadW(Wb, 0, 0);
#pragma unroll
        for (int ks = 0; ks < 8; ++ks) {
            if (ks < 7) loadW(Wb, (ks + 1) & 1, ks + 1);  // next step's B-frags in flight
            f16x8 a[4];
#pragma unroll
            for (int mt = 0; mt < 4; ++mt)
                a[mt] = *(const f16x8*)(hb + (wm * 64 + mt * 16 + mh) * HSTR + ks * 32 + g * 8);
            __builtin_amdgcn_s_setprio(1);
#pragma unroll
            for (int nt = 0; nt < 4; ++nt)
#pragma unroll
                for (int mt = 0; mt < 4; ++mt)
                    acc[mt][nt] = __builtin_amdgcn_mfma_f32_16x16x32_f16(a[mt], wr[ks & 1][nt], acc[mt][nt], 0, 0, 0);
            __builtin_amdgcn_s_setprio(0);
        }
        __syncthreads();  // all reads of h done before overwrite
        if (l == 0) {
            float bv[4];
#pragma unroll
            for (int nt = 0; nt < 4; ++nt) bv[nt] = b2[s * H + wn * 64 + nt * 16 + mh];
#pragma unroll
            for (int mt = 0; mt < 4; ++mt)
#pragma unroll
                for (int nt = 0; nt < 4; ++nt)
#pragma unroll
                    for (int r = 0; r < 4; ++r) {
                        float v = acc[mt][nt][r] + bv[nt];
                        v = __fdividef(v, 1.f + __expf(-v));
                        hb[(wm * 64 + mt * 16 + g * 4 + r) * HSTR + wn * 64 + nt * 16 + mh] = (_Float16)v;
                        acc[mt][nt][r] = 0.f;
                    }
            __syncthreads();
        }
    }

    // ---------------- layer 3 activation + layer 4 dot + reduce ----------------
    {
        float bv[4], w4v[4];
#pragma unroll
        for (int nt = 0; nt < 4; ++nt) {
            int col = wn * 64 + nt * 16 + mh;
            bv[nt] = b3[s * H + col];
            w4v[nt] = W4[s * H + col];
        }
#pragma unroll
        for (int mt = 0; mt < 4; ++mt)
#pragma unroll
            for (int r = 0; r < 4; ++r) {
                float v = 0.f;
#pragma unroll
                for (int nt = 0; nt < 4; ++nt) {
                    float h = acc[mt][nt][r] + bv[nt];
                    h = __fdividef(h, 1.f + __expf(-h));
                    v += h * w4v[nt];
                }
                v += __shfl_xor(v, 1);
                v += __shfl_xor(v, 2);
                v += __shfl_xor(v, 4);
                v += __shfl_xor(v, 8);
                if (mh == r) e_lds[wn][wm * 64 + mt * 16 + g * 4 + r] = v;
            }
    }
    __syncthreads();
    // plain coalesced store of per-atom energies -- no global atomics
    if (tid < BM) {
        float e = b4[s] + e_lds[0][tid] + e_lds[1][tid] + e_lds[2][tid] + e_lds[3][tid];
        Eout[(size_t)s * NATOMS + tile * BM + tid] = e;
    }
}

// stage 1: per-block private LDS histogram of 1024 atoms -> partial[512] per block
__global__ __launch_bounds__(256) void reduce1(
    const float* __restrict__ E, const int* __restrict__ ids,
    float* __restrict__ partials)
{
    __shared__ float tbl[NSTRUCT];
    const int b = blockIdx.x;
    const int tid = threadIdx.x;
    tbl[tid] = 0.f;
    tbl[tid + 256] = 0.f;
    __syncthreads();
    const int base = b * APB;
#pragma unroll
    for (int i = 0; i < APB / 256; ++i) {
        int a = base + i * 256 + tid;
        atomicAdd(&tbl[ids[a]], E[a]);
    }
    __syncthreads();
    partials[(size_t)b * NSTRUCT + tid] = tbl[tid];
    partials[(size_t)b * NSTRUCT + tid + 256] = tbl[tid + 256];
}

// stage 2: sum 128 partial tables + shift -> out
__global__ __launch_bounds__(512) void reduce2(
    const float* __restrict__ partials, const float* __restrict__ shift,
    float* __restrict__ out)
{
    const int i = threadIdx.x;
    float v = shift[0];
#pragma unroll 8
    for (int b = 0; b < RBLK; ++b) v += partials[(size_t)b * NSTRUCT + i];
    out[i] = v;
}

extern "C" void kernel_launch(void* const* d_in, const int* in_sizes, int n_in,
                              void* d_out, int out_size, void* d_ws, size_t ws_size,
                              hipStream_t stream) {
    const float* X   = (const float*)d_in[0];
    const int*   ids = (const int*)d_in[1];
    const float* W1  = (const float*)d_in[2];
    const float* b1  = (const float*)d_in[3];
    const float* W2  = (const float*)d_in[4];
    const float* b2  = (const float*)d_in[5];
    const float* W3  = (const float*)d_in[6];
    const float* b3  = (const float*)d_in[7];
    const float* W4  = (const float*)d_in[8];
    const float* b4  = (const float*)d_in[9];
    const float* shift = (const float*)d_in[10];

    // ws layout: W1p 1MB | W2p 512KB | W3p 512KB | E 512KB | partials 256KB
    _Float16* W1p = (_Float16*)d_ws;
    _Float16* W2p = W1p + (size_t)S * 4 * 64 * 512;
    _Float16* W3p = W2p + (size_t)S * 4 * 32 * 512;
    float* E = (float*)(W3p + (size_t)S * 4 * 32 * 512);
    float* partials = E + (size_t)S * NATOMS;

    pack_w<<<2048, 256, 0, stream>>>(W1, W1p, 16);
    pack_w<<<1024, 256, 0, stream>>>(W2, W2p, 8);
    pack_w<<<1024, 256, 0, stream>>>(W3, W3p, 8);

    dim3 grid(NATOMS / BM, S);
    fused_mlp<<<grid, 512, 0, stream>>>(X, W1p, W2p, W3p, b1, b2, b3, W4, b4, E);

    reduce1<<<RBLK, 256, 0, stream>>>(E, ids, partials);
    reduce2<<<1, 512, 0, stream>>>(partials, shift, (float*)d_out);
}

// Round 15
// 177.591 us; speedup vs baseline: 1.0195x; 1.0195x over previous
//
#include <hip/hip_runtime.h>

typedef _Float16 f16x8 __attribute__((ext_vector_type(8)));
typedef _Float16 f16x4 __attribute__((ext_vector_type(4)));
typedef float f32x4 __attribute__((ext_vector_type(4)));

static constexpr int S = 4;
static constexpr int NATOMS = 32768;
static constexpr int FIN = 512;
static constexpr int H = 256;
static constexpr int BM = 128;   // atoms per block
static constexpr int XSTR = 36;  // 32 fp16 + 4 pad (72B rows: 2-way banks, free)
static constexpr int HSTR = 264; // h plane: 256 cols + 8 pad fp16 (528B rows, 2-way)
static constexpr int NSTRUCT = 512;
static constexpr int RBLK = 128;
static constexpr int APB = (S * NATOMS) / RBLK;  // 1024

// ---- weight packing: fp32 [S][K][H] -> per-(s,wn) consumption-order fp16 stream
// Stream layout: [s*4 + (ntile>>2)][p][lane][8]; p = kt*4 + (ntile&3).
__global__ void pack_w(const float* __restrict__ W, _Float16* __restrict__ dst, int KT) {
    int idx = blockIdx.x * 256 + threadIdx.x;
    int j = idx & 7;
    int lane = (idx >> 3) & 63;
    int rest = idx >> 9;
    int kt = rest % KT;
    int t2 = rest / KT;            // s*16 + ntile
    int K = KT * 32;
    int k = kt * 32 + (lane >> 4) * 8 + j;
    int ntile = t2 & 15;
    int s = t2 >> 4;
    int n = ntile * 16 + (lane & 15);
    int p = kt * 4 + (ntile & 3);
    size_t o = ((((size_t)(s * 4 + (ntile >> 2))) * (KT * 4) + p) * 64 + lane) * 8 + j;
    dst[o] = (_Float16)W[((size_t)s * K + k) * H + n];
}

// ================= kernel A: layer 1 GEMM, X fp32 -> h1 fp16 =================
__global__ __launch_bounds__(512, 3) void l1gemm(
    const float* __restrict__ X, const _Float16* __restrict__ W1p,
    const float* __restrict__ b1, _Float16* __restrict__ h1)
{
    __shared__ _Float16 xlds[3 * BM * XSTR];   // 27648B only -> more blocks/CU

    const int s = blockIdx.y;
    const int tile = blockIdx.x;
    const int tid = threadIdx.x;
    const int rw = __builtin_amdgcn_readfirstlane(tid >> 6);
    const int wm = rw >> 2;
    const int wn = rw & 3;
    const int lane = tid & 63;
    const int g = lane >> 4;
    const int mh = lane & 15;
    const int srow = tid >> 2;
    const int cq = tid & 3;

    const float* Xb = X + (size_t)(s * NATOMS + tile * BM) * FIN;
    const _Float16* Wb1 = W1p + ((size_t)(s * 4 + wn)) * (64 * 512) + lane * 8;

    f32x4 acc[4][4];
#pragma unroll
    for (int i = 0; i < 4; ++i)
#pragma unroll
        for (int j = 0; j < 4; ++j)
            acc[i][j] = f32x4{0.f, 0.f, 0.f, 0.f};

    f32x4 ld[3][2];
    auto loadc = [&](int slot, int c) {
        const float* p = Xb + (size_t)srow * FIN + c * 32 + cq * 8;
        ld[slot][0] = *(const f32x4*)(p);
        ld[slot][1] = *(const f32x4*)(p + 4);
    };
    auto storec = [&](int slot, int c) {
        _Float16* xb = xlds + (c % 3) * (BM * XSTR);
#pragma unroll
        for (int i = 0; i < 2; ++i) {
            f16x4 v;
#pragma unroll
            for (int j = 0; j < 4; ++j) v[j] = (_Float16)ld[slot][i][j];
            *(f16x4*)(xb + srow * XSTR + cq * 8 + i * 4) = v;
        }
    };
    auto l1mfma = [&](int c) {
        const _Float16* xb = xlds + (c % 3) * (BM * XSTR);
        f16x8 a[4];
#pragma unroll
        for (int mt = 0; mt < 4; ++mt)
            a[mt] = *(const f16x8*)(xb + (wm * 64 + mt * 16 + mh) * XSTR + g * 8);
        __builtin_amdgcn_s_setprio(1);
#pragma unroll
        for (int nt = 0; nt < 4; ++nt) {
            f16x8 b = *(const f16x8*)(Wb1 + (c * 4 + nt) * 512);
#pragma unroll
            for (int mt = 0; mt < 4; ++mt)
                acc[mt][nt] = __builtin_amdgcn_mfma_f32_16x16x32_f16(a[mt], b, acc[mt][nt], 0, 0, 0);
        }
        __builtin_amdgcn_s_setprio(0);
    };

    loadc(0, 0);
    loadc(1, 1);
    loadc(2, 2);
    storec(0, 0);
    asm volatile("s_waitcnt lgkmcnt(0)" ::: "memory");
    __builtin_amdgcn_s_barrier();
#pragma unroll
    for (int c = 0; c < 16; ++c) {
        if (c < 15) storec((c + 1) % 3, c + 1);
        if (c < 13) loadc(c % 3, c + 3);
        l1mfma(c);
        asm volatile("s_waitcnt lgkmcnt(0)" ::: "memory");
        __builtin_amdgcn_s_barrier();
    }

    // bias + silu -> h1 global (fp16, [s][atom][256] linear)
    _Float16* Ho = h1 + ((size_t)(s * NATOMS + tile * BM)) * H;
    float bv[4];
#pragma unroll
    for (int nt = 0; nt < 4; ++nt) bv[nt] = b1[s * H + wn * 64 + nt * 16 + mh];
#pragma unroll
    for (int mt = 0; mt < 4; ++mt)
#pragma unroll
        for (int nt = 0; nt < 4; ++nt)
#pragma unroll
            for (int r = 0; r < 4; ++r) {
                float v = acc[mt][nt][r] + bv[nt];
                v = __fdividef(v, 1.f + __expf(-v));
                Ho[(size_t)(wm * 64 + mt * 16 + g * 4 + r) * H + wn * 64 + nt * 16 + mh] = (_Float16)v;
            }
}

// ============ kernel B: layers 2-4, h1 fp16 -> per-atom energies ============
__global__ __launch_bounds__(512, 3) void l234(
    const _Float16* __restrict__ h1,
    const _Float16* __restrict__ W2p, const _Float16* __restrict__ W3p,
    const float* __restrict__ b2, const float* __restrict__ b3,
    const float* __restrict__ W4, const float* __restrict__ b4,
    float* __restrict__ Eout)
{
    __shared__ _Float16 hb[BM * HSTR];
    __shared__ float e_lds[4][BM];

    const int s = blockIdx.y;
    const int tile = blockIdx.x;
    const int tid = threadIdx.x;
    const int rw = __builtin_amdgcn_readfirstlane(tid >> 6);
    const int wm = rw >> 2;
    const int wn = rw & 3;
    const int lane = tid & 63;
    const int g = lane >> 4;
    const int mh = lane & 15;

    const _Float16* Wb2 = W2p + ((size_t)(s * 4 + wn)) * (32 * 512) + lane * 8;
    const _Float16* Wb3 = W3p + ((size_t)(s * 4 + wn)) * (32 * 512) + lane * 8;

    // ---- one-shot h1 tile load into padded LDS (no conversion needed) ----
    const _Float16* Hb = h1 + ((size_t)(s * NATOMS + tile * BM)) * H;
#pragma unroll
    for (int i = 0; i < 8; ++i) {
        int gi = i * 512 + tid;              // 4096 granules of 16B
        int row = gi >> 5, gr = gi & 31;
        f16x8 v = *(const f16x8*)(Hb + (size_t)row * H + gr * 8);
        *(f16x8*)(hb + row * HSTR + gr * 8) = v;
    }
    __syncthreads();

    f32x4 acc[4][4];
#pragma unroll
    for (int i = 0; i < 4; ++i)
#pragma unroll
        for (int j = 0; j < 4; ++j)
            acc[i][j] = f32x4{0.f, 0.f, 0.f, 0.f};

    for (int l = 0; l < 2; ++l) {
        const _Float16* Wb = l ? Wb3 : Wb2;
#pragma unroll
        for (int ks = 0; ks < 8; ++ks) {
            f16x8 a[4];
#pragma unroll
            for (int mt = 0; mt < 4; ++mt)
                a[mt] = *(const f16x8*)(hb + (wm * 64 + mt * 16 + mh) * HSTR + ks * 32 + g * 8);
            __builtin_amdgcn_s_setprio(1);
#pragma unroll
            for (int nt = 0; nt < 4; ++nt) {
                f16x8 b = *(const f16x8*)(Wb + (ks * 4 + nt) * 512);
#pragma unroll
                for (int mt = 0; mt < 4; ++mt)
                    acc[mt][nt] = __builtin_amdgcn_mfma_f32_16x16x32_f16(a[mt], b, acc[mt][nt], 0, 0, 0);
            }
            __builtin_amdgcn_s_setprio(0);
        }
        __syncthreads();  // all reads of h done before overwrite
        if (l == 0) {
            float bv[4];
#pragma unroll
            for (int nt = 0; nt < 4; ++nt) bv[nt] = b2[s * H + wn * 64 + nt * 16 + mh];
#pragma unroll
            for (int mt = 0; mt < 4; ++mt)
#pragma unroll
                for (int nt = 0; nt < 4; ++nt)
#pragma unroll
                    for (int r = 0; r < 4; ++r) {
                        float v = acc[mt][nt][r] + bv[nt];
                        v = __fdividef(v, 1.f + __expf(-v));
                        hb[(wm * 64 + mt * 16 + g * 4 + r) * HSTR + wn * 64 + nt * 16 + mh] = (_Float16)v;
                        acc[mt][nt][r] = 0.f;
                    }
            __syncthreads();
        }
    }

    // ---- layer 3 activation + layer 4 dot + reduce ----
    {
        float bv[4], w4v[4];
#pragma unroll
        for (int nt = 0; nt < 4; ++nt) {
            int col = wn * 64 + nt * 16 + mh;
            bv[nt] = b3[s * H + col];
            w4v[nt] = W4[s * H + col];
        }
#pragma unroll
        for (int mt = 0; mt < 4; ++mt)
#pragma unroll
            for (int r = 0; r < 4; ++r) {
                float v = 0.f;
#pragma unroll
                for (int nt = 0; nt < 4; ++nt) {
                    float h = acc[mt][nt][r] + bv[nt];
                    h = __fdividef(h, 1.f + __expf(-h));
                    v += h * w4v[nt];
                }
                v += __shfl_xor(v, 1);
                v += __shfl_xor(v, 2);
                v += __shfl_xor(v, 4);
                v += __shfl_xor(v, 8);
                if (mh == r) e_lds[wn][wm * 64 + mt * 16 + g * 4 + r] = v;
            }
    }
    __syncthreads();
    if (tid < BM) {
        float e = b4[s] + e_lds[0][tid] + e_lds[1][tid] + e_lds[2][tid] + e_lds[3][tid];
        Eout[(size_t)s * NATOMS + tile * BM + tid] = e;
    }
}

// stage 1: per-block private LDS histogram of 1024 atoms -> partial[512] per block
__global__ __launch_bounds__(256) void reduce1(
    const float* __restrict__ E, const int* __restrict__ ids,
    float* __restrict__ partials)
{
    __shared__ float tbl[NSTRUCT];
    const int b = blockIdx.x;
    const int tid = threadIdx.x;
    tbl[tid] = 0.f;
    tbl[tid + 256] = 0.f;
    __syncthreads();
    const int base = b * APB;
#pragma unroll
    for (int i = 0; i < APB / 256; ++i) {
        int a = base + i * 256 + tid;
        atomicAdd(&tbl[ids[a]], E[a]);
    }
    __syncthreads();
    partials[(size_t)b * NSTRUCT + tid] = tbl[tid];
    partials[(size_t)b * NSTRUCT + tid + 256] = tbl[tid + 256];
}

// stage 2: sum 128 partial tables + shift -> out
__global__ __launch_bounds__(512) void reduce2(
    const float* __restrict__ partials, const float* __restrict__ shift,
    float* __restrict__ out)
{
    const int i = threadIdx.x;
    float v = shift[0];
#pragma unroll 8
    for (int b = 0; b < RBLK; ++b) v += partials[(size_t)b * NSTRUCT + i];
    out[i] = v;
}

extern "C" void kernel_launch(void* const* d_in, const int* in_sizes, int n_in,
                              void* d_out, int out_size, void* d_ws, size_t ws_size,
                              hipStream_t stream) {
    const float* X   = (const float*)d_in[0];
    const int*   ids = (const int*)d_in[1];
    const float* W1  = (const float*)d_in[2];
    const float* b1  = (const float*)d_in[3];
    const float* W2  = (const float*)d_in[4];
    const float* b2  = (const float*)d_in[5];
    const float* W3  = (const float*)d_in[6];
    const float* b3  = (const float*)d_in[7];
    const float* W4  = (const float*)d_in[8];
    const float* b4  = (const float*)d_in[9];
    const float* shift = (const float*)d_in[10];

    // ws layout: W1p 1MB | W2p 512KB | W3p 512KB | E 512KB | partials 256KB | h1 67MB
    _Float16* W1p = (_Float16*)d_ws;
    _Float16* W2p = W1p + (size_t)S * 4 * 64 * 512;
    _Float16* W3p = W2p + (size_t)S * 4 * 32 * 512;
    float* E = (float*)(W3p + (size_t)S * 4 * 32 * 512);
    float* partials = E + (size_t)S * NATOMS;
    _Float16* h1 = (_Float16*)(partials + (size_t)RBLK * NSTRUCT);

    pack_w<<<2048, 256, 0, stream>>>(W1, W1p, 16);
    pack_w<<<1024, 256, 0, stream>>>(W2, W2p, 8);
    pack_w<<<1024, 256, 0, stream>>>(W3, W3p, 8);

    dim3 grid(NATOMS / BM, S);
    l1gemm<<<grid, 512, 0, stream>>>(X, W1p, b1, h1);
    l234<<<grid, 512, 0, stream>>>(h1, W2p, W3p, b2, b3, W4, b4, E);

    reduce1<<<RBLK, 256, 0, stream>>>(E, ids, partials);
    reduce2<<<1, 512, 0, stream>>>(partials, shift, (float*)d_out);
}

// Round 16
// 167.841 us; speedup vs baseline: 1.0787x; 1.0581x over previous
//
#include <hip/hip_runtime.h>

typedef _Float16 f16x8 __attribute__((ext_vector_type(8)));
typedef _Float16 f16x4 __attribute__((ext_vector_type(4)));
typedef float f32x4 __attribute__((ext_vector_type(4)));
typedef float f32x16 __attribute__((ext_vector_type(16)));

static constexpr int S = 4;
static constexpr int NATOMS = 32768;
static constexpr int FIN = 512;
static constexpr int H = 256;
static constexpr int BM = 128;   // atoms per block
static constexpr int XSTR = 36;  // 32 fp16 + 4 pad (72B rows: 2-way banks for 32-row groups)
static constexpr int HSTR = 264; // h plane rows 528B; granule-XOR swizzle fixes 4-way
static constexpr int NSTRUCT = 512;
static constexpr int RBLK = 128;
static constexpr int APB = (S * NATOMS) / RBLK;  // 1024

// ---- weight packing for 32x32x16 frags: per-(s,wn) consumption-order stream ----
// frag elem (lane,j): n = wn*64 + nt*32 + (lane&31); k = (c*2+kk)*16 + (lane>>5)*8 + j
// p = c*4 + kk*2 + nt  (matches kernel loop order).  P = 64 (L1) / 32 (L2,L3)
__global__ void pack_w32(const float* __restrict__ W, _Float16* __restrict__ dst, int P) {
    int idx = blockIdx.x * 256 + threadIdx.x;
    int j = idx & 7;
    int lane = (idx >> 3) & 63;
    int p = (idx >> 9) % P;
    int t = (idx >> 9) / P;
    int wn = t & 3;
    int s = t >> 2;
    int K = P * 8;                // 512 for L1, 256 for L2/3
    int c = p >> 2, kk = (p >> 1) & 1, nt = p & 1;
    int k = (c * 2 + kk) * 16 + (lane >> 5) * 8 + j;
    int n = wn * 64 + nt * 32 + (lane & 31);
    dst[((size_t)idx & ~511) + lane * 8 + j] = (_Float16)W[((size_t)s * K + k) * H + n];
}

__global__ __launch_bounds__(512, 3) void fused_mlp(
    const float* __restrict__ X,
    const _Float16* __restrict__ W1p, const _Float16* __restrict__ W2p,
    const _Float16* __restrict__ W3p,
    const float* __restrict__ b1, const float* __restrict__ b2,
    const float* __restrict__ b3,
    const float* __restrict__ W4, const float* __restrict__ b4,
    float* __restrict__ Eout)
{
    // union: X fp16 triple buffer [3][128][36] (27648B) aliased by h fp16 plane
    // [128][264] (67584B). h written only after all layer-1 LDS reads are done.
    __shared__ _Float16 smem[BM * HSTR];
    __shared__ float e_lds[4][BM];

    const int s = blockIdx.y;
    const int tile = blockIdx.x;
    const int tid = threadIdx.x;
    const int rw = __builtin_amdgcn_readfirstlane(tid >> 6);
    const int wm = rw >> 2;        // 0..1: M-half (64 atoms)
    const int wn = rw & 3;         // 0..3: 64-col slice of H
    const int lane = tid & 63;
    const int c32 = lane & 31;     // A row / B,C col within 32-tile
    const int hi = lane >> 5;      // k-half for A/B; +4 rows for C
    const int srow = tid >> 2;     // staging row (128 rows, 4 threads/row)
    const int cq = tid & 3;        // staging col group (8 floats)

    const float* Xb = X + (size_t)(s * NATOMS + tile * BM) * FIN;
    _Float16* hb = smem;

    // per-(s,wn) contiguous consumption-order weight streams
    const _Float16* Wb1 = W1p + ((size_t)(s * 4 + wn)) * (64 * 512) + lane * 8;
    const _Float16* Wb2 = W2p + ((size_t)(s * 4 + wn)) * (32 * 512) + lane * 8;
    const _Float16* Wb3 = W3p + ((size_t)(s * 4 + wn)) * (32 * 512) + lane * 8;

    f32x16 acc[2][2];
#pragma unroll
    for (int i = 0; i < 2; ++i)
#pragma unroll
        for (int j = 0; j < 2; ++j)
            acc[i][j] = (f32x16)(0.f);

    // ---- layer-1 staging: global->reg (f32) -> cvt once -> LDS (f16) ----
    f32x4 ld[3][2];
    auto loadc = [&](int slot, int c) {
        const float* p = Xb + (size_t)srow * FIN + c * 32 + cq * 8;
        ld[slot][0] = *(const f32x4*)(p);
        ld[slot][1] = *(const f32x4*)(p + 4);
    };
    auto storec = [&](int slot, int c) {
        _Float16* xb = smem + (c % 3) * (BM * XSTR);
#pragma unroll
        for (int i = 0; i < 2; ++i) {
            f16x4 v;
#pragma unroll
            for (int j = 0; j < 4; ++j) v[j] = (_Float16)ld[slot][i][j];
            *(f16x4*)(xb + srow * XSTR + cq * 8 + i * 4) = v;
        }
    };
    // A-frag (mt,kk): rows wm*64+mt*32+c32 (2-way banks at XSTR=36), k=kk*16+hi*8
    auto l1mfma = [&](int c) {
        const _Float16* xb = smem + (c % 3) * (BM * XSTR);
#pragma unroll
        for (int kk = 0; kk < 2; ++kk) {
            f16x8 a[2];
#pragma unroll
            for (int mt = 0; mt < 2; ++mt)
                a[mt] = *(const f16x8*)(xb + (wm * 64 + mt * 32 + c32) * XSTR + kk * 16 + hi * 8);
            __builtin_amdgcn_s_setprio(1);
#pragma unroll
            for (int nt = 0; nt < 2; ++nt) {
                f16x8 b = *(const f16x8*)(Wb1 + ((c * 4 + kk * 2 + nt)) * 512);
#pragma unroll
                for (int mt = 0; mt < 2; ++mt)
                    acc[mt][nt] = __builtin_amdgcn_mfma_f32_32x32x16_f16(a[mt], b, acc[mt][nt], 0, 0, 0);
            }
            __builtin_amdgcn_s_setprio(0);
        }
    };

    // ---------------- layer 1: [128x512] @ [512x256], 16 chunks ----------------
    loadc(0, 0);
    loadc(1, 1);
    loadc(2, 2);
    storec(0, 0);
    asm volatile("s_waitcnt lgkmcnt(0)" ::: "memory");
    __builtin_amdgcn_s_barrier();
#pragma unroll
    for (int c = 0; c < 16; ++c) {
        if (c < 15) storec((c + 1) % 3, c + 1);
        if (c < 13) loadc(c % 3, c + 3);
        l1mfma(c);
        asm volatile("s_waitcnt lgkmcnt(0)" ::: "memory");
        __builtin_amdgcn_s_barrier();
    }
    __syncthreads();  // full drain before h overwrites the X union

    // h write with granule swizzle: g8' = g8 ^ ((row>>3)&3)
    auto hwrite = [&](int grow, int col, float v) {
        int g8 = (col >> 3) ^ ((grow >> 3) & 3);
        hb[grow * HSTR + (g8 << 3) + (col & 7)] = (_Float16)v;
    };
    auto silu_epi = [&](const float* bias) {
#pragma unroll
        for (int nt = 0; nt < 2; ++nt) {
            float bv = bias[s * H + wn * 64 + nt * 32 + c32];
#pragma unroll
            for (int mt = 0; mt < 2; ++mt)
#pragma unroll
                for (int r = 0; r < 16; ++r) {
                    float v = acc[mt][nt][r] + bv;
                    v = __fdividef(v, 1.f + __expf(-v));
                    int grow = wm * 64 + mt * 32 + (r & 3) + 8 * (r >> 2) + 4 * hi;
                    hwrite(grow, wn * 64 + nt * 32 + c32, v);
                    acc[mt][nt][r] = 0.f;
                }
        }
    };

    silu_epi(b1);
    __syncthreads();

    // ---------------- layers 2 and 3: [128x256] @ [256x256] ----------------
    for (int l = 0; l < 2; ++l) {
        const _Float16* Wb = l ? Wb3 : Wb2;
#pragma unroll
        for (int ks = 0; ks < 8; ++ks) {
#pragma unroll
            for (int kk = 0; kk < 2; ++kk) {
                f16x8 a[2];
#pragma unroll
                for (int mt = 0; mt < 2; ++mt) {
                    int grow = wm * 64 + mt * 32 + c32;
                    int g8 = (ks * 4 + kk * 2 + hi) ^ ((grow >> 3) & 3);
                    a[mt] = *(const f16x8*)(hb + grow * HSTR + (g8 << 3));
                }
                __builtin_amdgcn_s_setprio(1);
#pragma unroll
                for (int nt = 0; nt < 2; ++nt) {
                    f16x8 b = *(const f16x8*)(Wb + ((ks * 4 + kk * 2 + nt)) * 512);
#pragma unroll
                    for (int mt = 0; mt < 2; ++mt)
                        acc[mt][nt] = __builtin_amdgcn_mfma_f32_32x32x16_f16(a[mt], b, acc[mt][nt], 0, 0, 0);
                }
                __builtin_amdgcn_s_setprio(0);
            }
        }
        __syncthreads();  // all reads of h done before overwrite
        if (l == 0) {
            silu_epi(b2);
            __syncthreads();
        }
    }

    // ---------------- layer 3 activation + layer 4 dot + reduce ----------------
    {
#pragma unroll
        for (int mt = 0; mt < 2; ++mt)
#pragma unroll
            for (int r = 0; r < 16; ++r) {
                float v = 0.f;
#pragma unroll
                for (int nt = 0; nt < 2; ++nt) {
                    int col = wn * 64 + nt * 32 + c32;
                    float h = acc[mt][nt][r] + b3[s * H + col];
                    h = __fdividef(h, 1.f + __expf(-h));
                    v += h * W4[s * H + col];
                }
                // sum over the 32 col-lanes of this hi-half (row is uniform per half)
                v += __shfl_xor(v, 1);
                v += __shfl_xor(v, 2);
                v += __shfl_xor(v, 4);
                v += __shfl_xor(v, 8);
                v += __shfl_xor(v, 16);
                if (c32 == r) {
                    int grow = wm * 64 + mt * 32 + (r & 3) + 8 * (r >> 2) + 4 * hi;
                    e_lds[wn][grow] = v;
                }
            }
    }
    __syncthreads();
    // plain coalesced store of per-atom energies -- no global atomics
    if (tid < BM) {
        float e = b4[s] + e_lds[0][tid] + e_lds[1][tid] + e_lds[2][tid] + e_lds[3][tid];
        Eout[(size_t)s * NATOMS + tile * BM + tid] = e;
    }
}

// stage 1: per-block private LDS histogram of 1024 atoms -> partial[512] per block
__global__ __launch_bounds__(256) void reduce1(
    const float* __restrict__ E, const int* __restrict__ ids,
    float* __restrict__ partials)
{
    __shared__ float tbl[NSTRUCT];
    const int b = blockIdx.x;
    const int tid = threadIdx.x;
    tbl[tid] = 0.f;
    tbl[tid + 256] = 0.f;
    __syncthreads();
    const int base = b * APB;
#pragma unroll
    for (int i = 0; i < APB / 256; ++i) {
        int a = base + i * 256 + tid;
        atomicAdd(&tbl[ids[a]], E[a]);
    }
    __syncthreads();
    partials[(size_t)b * NSTRUCT + tid] = tbl[tid];
    partials[(size_t)b * NSTRUCT + tid + 256] = tbl[tid + 256];
}

// stage 2: sum 128 partial tables + shift -> out
__global__ __launch_bounds__(512) void reduce2(
    const float* __restrict__ partials, const float* __restrict__ shift,
    float* __restrict__ out)
{
    const int i = threadIdx.x;
    float v = shift[0];
#pragma unroll 8
    for (int b = 0; b < RBLK; ++b) v += partials[(size_t)b * NSTRUCT + i];
    out[i] = v;
}

extern "C" void kernel_launch(void* const* d_in, const int* in_sizes, int n_in,
                              void* d_out, int out_size, void* d_ws, size_t ws_size,
                              hipStream_t stream) {
    const float* X   = (const float*)d_in[0];
    const int*   ids = (const int*)d_in[1];
    const float* W1  = (const float*)d_in[2];
    const float* b1  = (const float*)d_in[3];
    const float* W2  = (const float*)d_in[4];
    const float* b2  = (const float*)d_in[5];
    const float* W3  = (const float*)d_in[6];
    const float* b3  = (const float*)d_in[7];
    const float* W4  = (const float*)d_in[8];
    const float* b4  = (const float*)d_in[9];
    const float* shift = (const float*)d_in[10];

    // ws layout: W1p 1MB | W2p 512KB | W3p 512KB | E 512KB | partials 256KB
    _Float16* W1p = (_Float16*)d_ws;
    _Float16* W2p = W1p + (size_t)S * 4 * 64 * 512;
    _Float16* W3p = W2p + (size_t)S * 4 * 32 * 512;
    float* E = (float*)(W3p + (size_t)S * 4 * 32 * 512);
    float* partials = E + (size_t)S * NATOMS;

    pack_w32<<<2048, 256, 0, stream>>>(W1, W1p, 64);
    pack_w32<<<1024, 256, 0, stream>>>(W2, W2p, 32);
    pack_w32<<<1024, 256, 0, stream>>>(W3, W3p, 32);

    dim3 grid(NATOMS / BM, S);
    fused_mlp<<<grid, 512, 0, stream>>>(X, W1p, W2p, W3p, b1, b2, b3, W4, b4, E);

    reduce1<<<RBLK, 256, 0, stream>>>(E, ids, partials);
    reduce2<<<1, 512, 0, stream>>>(partials, shift, (float*)d_out);
}